// Round 2
// baseline (1408.386 us; speedup 1.0000x reference)
//
#include <hip/hip_runtime.h>

#define N_NODES 100000
#define N_EDGES 1600000
#define DIM 128
#define NLAYERS 3
#define NGRAPHS 512
#define BN_EPS 1e-5f

#define RT 64      // rows per MLP block
#define KC 32      // k-chunk
#define XP 36      // Xs padded stride (words) -> 2-way-free LDS banks
#define WP 132     // Ws padded stride
#define HP 132     // Hs padded stride

// ---------------- CSR build ----------------
__global__ __launch_bounds__(256) void hist_kernel(const int* __restrict__ dst,
                                                   int* __restrict__ deg) {
  for (int e = blockIdx.x * blockDim.x + threadIdx.x; e < N_EDGES;
       e += gridDim.x * blockDim.x)
    atomicAdd(&deg[dst[e]], 1);
}

__global__ __launch_bounds__(1024) void scan_kernel(const int* __restrict__ deg,
                                                    int* __restrict__ row_ptr,
                                                    int* __restrict__ cursor) {
  __shared__ int sums[1024];
  const int t = threadIdx.x;
  const int chunk = (N_NODES + 1023) >> 10;  // 98
  const int s0 = t * chunk;
  const int s1 = min(s0 + chunk, N_NODES);
  int s = 0;
  for (int i = s0; i < s1; ++i) s += deg[i];
  sums[t] = s;
  __syncthreads();
  for (int off = 1; off < 1024; off <<= 1) {
    int v = (t >= off) ? sums[t - off] : 0;
    __syncthreads();
    sums[t] += v;
    __syncthreads();
  }
  int run = (t == 0) ? 0 : sums[t - 1];  // exclusive prefix
  for (int i = s0; i < s1; ++i) {
    row_ptr[i] = run;
    cursor[i] = run;
    run += deg[i];
  }
  if (t == 1023) row_ptr[N_NODES] = run;  // t=1023 chunk empty -> run == total
}

__global__ __launch_bounds__(256) void fill_kernel(const int* __restrict__ src,
                                                   const int* __restrict__ dst,
                                                   int* __restrict__ cursor,
                                                   int* __restrict__ col) {
  for (int e = blockIdx.x * blockDim.x + threadIdx.x; e < N_EDGES;
       e += gridDim.x * blockDim.x) {
    const int d = dst[e];
    const int pos = atomicAdd(&cursor[d], 1);
    col[pos] = src[e];
  }
}

// ---------------- aggregation: agg[i] = z[i] + sum_{j in N(i)} z[j] ----------------
__global__ __launch_bounds__(256) void agg_kernel(const float* __restrict__ zin,
                                                  int zstride,
                                                  const int* __restrict__ row_ptr,
                                                  const int* __restrict__ col,
                                                  float* __restrict__ agg) {
  const int w = (blockIdx.x * 256 + threadIdx.x) >> 6;  // one wave per node
  const int lane = threadIdx.x & 63;
  if (w >= N_NODES) return;
  const int start = row_ptr[w];
  const int end = row_ptr[w + 1];

  float2 acc = ((const float2*)(zin + (size_t)w * zstride))[lane];  // + z[i]
  int j = start;
  // 8 independent row-loads in flight for latency hiding (avg degree 16)
  for (; j + 8 <= end; j += 8) {
    const int c0 = col[j], c1 = col[j + 1], c2 = col[j + 2], c3 = col[j + 3];
    const int c4 = col[j + 4], c5 = col[j + 5], c6 = col[j + 6], c7 = col[j + 7];
    const float2 v0 = ((const float2*)(zin + (size_t)c0 * zstride))[lane];
    const float2 v1 = ((const float2*)(zin + (size_t)c1 * zstride))[lane];
    const float2 v2 = ((const float2*)(zin + (size_t)c2 * zstride))[lane];
    const float2 v3 = ((const float2*)(zin + (size_t)c3 * zstride))[lane];
    const float2 v4 = ((const float2*)(zin + (size_t)c4 * zstride))[lane];
    const float2 v5 = ((const float2*)(zin + (size_t)c5 * zstride))[lane];
    const float2 v6 = ((const float2*)(zin + (size_t)c6 * zstride))[lane];
    const float2 v7 = ((const float2*)(zin + (size_t)c7 * zstride))[lane];
    acc.x += ((v0.x + v1.x) + (v2.x + v3.x)) + ((v4.x + v5.x) + (v6.x + v7.x));
    acc.y += ((v0.y + v1.y) + (v2.y + v3.y)) + ((v4.y + v5.y) + (v6.y + v7.y));
  }
  for (; j + 4 <= end; j += 4) {
    const int c0 = col[j], c1 = col[j + 1], c2 = col[j + 2], c3 = col[j + 3];
    const float2 v0 = ((const float2*)(zin + (size_t)c0 * zstride))[lane];
    const float2 v1 = ((const float2*)(zin + (size_t)c1 * zstride))[lane];
    const float2 v2 = ((const float2*)(zin + (size_t)c2 * zstride))[lane];
    const float2 v3 = ((const float2*)(zin + (size_t)c3 * zstride))[lane];
    acc.x += (v0.x + v1.x) + (v2.x + v3.x);
    acc.y += (v0.y + v1.y) + (v2.y + v3.y);
  }
  for (; j < end; ++j) {
    const int c = col[j];
    const float2 v = ((const float2*)(zin + (size_t)c * zstride))[lane];
    acc.x += v.x;
    acc.y += v.y;
  }
  ((float2*)(agg + (size_t)w * DIM))[lane] = acc;
}

// ---------------- fused MLP: h2 = relu(relu(X@W1+b1)@W2+b2) + BN partials ----------------
__global__ __launch_bounds__(256) void mlp_kernel(
    const float* __restrict__ X,                       // agg [N,128]
    const float* __restrict__ W1, const float* __restrict__ b1,
    const float* __restrict__ W2, const float* __restrict__ b2,
    float* __restrict__ out,                           // d_out, row stride 384
    int lcol,                                          // l*128
    float* __restrict__ bnsum) {                       // [256]: sum | sumsq
  __shared__ float smem[32 * WP + RT * HP];  // 12672 floats = 50688 B
  float* Ws = smem;            // 32 x WP
  float* Xs = smem + 32 * WP;  // phase1: 64 x XP (2304 floats, fits region)
  float* Hs = smem + 32 * WP;  // phase2: 64 x HP
  float* red = smem + 32 * WP; // epilogue: 16 x 128

  const int tid = threadIdx.x;
  const int cg = tid & 15, rg = tid >> 4;
  const int c0 = cg * 8, r0 = rg * 4;
  const int n0 = blockIdx.x * RT;

  float4 acc[4][2];
#pragma unroll
  for (int rr = 0; rr < 4; ++rr) {
    acc[rr][0] = make_float4(0.f, 0.f, 0.f, 0.f);
    acc[rr][1] = make_float4(0.f, 0.f, 0.f, 0.f);
  }

  // ---- phase 1: h1 = relu(X@W1 + b1) ----
  for (int kc = 0; kc < DIM / KC; ++kc) {
    const int k0 = kc * KC;
    __syncthreads();
    {  // stage W1 rows k0..k0+31 (fully coalesced 16KB)
      const int kk = tid >> 3, q = tid & 7;
      const float4* s = (const float4*)(W1 + (size_t)(k0 + kk) * DIM + q * 16);
      float4* d = (float4*)(Ws + kk * WP + q * 16);
      d[0] = s[0]; d[1] = s[1]; d[2] = s[2]; d[3] = s[3];
    }
    {  // stage X cols k0..k0+31 for 64 rows
      const int i = tid >> 2, q = tid & 3;
      const int n = n0 + i;
      float4 v0 = make_float4(0, 0, 0, 0), v1 = v0;
      if (n < N_NODES) {
        const float4* s = (const float4*)(X + (size_t)n * DIM + k0 + q * 8);
        v0 = s[0]; v1 = s[1];
      }
      float4* d = (float4*)(Xs + i * XP + q * 8);
      d[0] = v0; d[1] = v1;
    }
    __syncthreads();
#pragma unroll 8
    for (int kk = 0; kk < KC; ++kk) {
      const float4 wA = *(const float4*)(Ws + kk * WP + c0);
      const float4 wB = *(const float4*)(Ws + kk * WP + c0 + 4);
#pragma unroll
      for (int rr = 0; rr < 4; ++rr) {
        const float a = Xs[(r0 + rr) * XP + kk];
        acc[rr][0].x = fmaf(a, wA.x, acc[rr][0].x);
        acc[rr][0].y = fmaf(a, wA.y, acc[rr][0].y);
        acc[rr][0].z = fmaf(a, wA.z, acc[rr][0].z);
        acc[rr][0].w = fmaf(a, wA.w, acc[rr][0].w);
        acc[rr][1].x = fmaf(a, wB.x, acc[rr][1].x);
        acc[rr][1].y = fmaf(a, wB.y, acc[rr][1].y);
        acc[rr][1].z = fmaf(a, wB.z, acc[rr][1].z);
        acc[rr][1].w = fmaf(a, wB.w, acc[rr][1].w);
      }
    }
  }

  // bias1 + relu -> Hs
  const float4 b1A = *(const float4*)(b1 + c0);
  const float4 b1B = *(const float4*)(b1 + c0 + 4);
  __syncthreads();
#pragma unroll
  for (int rr = 0; rr < 4; ++rr) {
    float4 hA, hB;
    hA.x = fmaxf(acc[rr][0].x + b1A.x, 0.f);
    hA.y = fmaxf(acc[rr][0].y + b1A.y, 0.f);
    hA.z = fmaxf(acc[rr][0].z + b1A.z, 0.f);
    hA.w = fmaxf(acc[rr][0].w + b1A.w, 0.f);
    hB.x = fmaxf(acc[rr][1].x + b1B.x, 0.f);
    hB.y = fmaxf(acc[rr][1].y + b1B.y, 0.f);
    hB.z = fmaxf(acc[rr][1].z + b1B.z, 0.f);
    hB.w = fmaxf(acc[rr][1].w + b1B.w, 0.f);
    *(float4*)(Hs + (r0 + rr) * HP + c0) = hA;
    *(float4*)(Hs + (r0 + rr) * HP + c0 + 4) = hB;
    acc[rr][0] = make_float4(0.f, 0.f, 0.f, 0.f);
    acc[rr][1] = make_float4(0.f, 0.f, 0.f, 0.f);
  }

  // ---- phase 2: h2 = relu(h1@W2 + b2) ----
  for (int kc = 0; kc < DIM / KC; ++kc) {
    const int k0 = kc * KC;
    __syncthreads();
    {  // stage W2 rows k0..k0+31
      const int kk = tid >> 3, q = tid & 7;
      const float4* s = (const float4*)(W2 + (size_t)(k0 + kk) * DIM + q * 16);
      float4* d = (float4*)(Ws + kk * WP + q * 16);
      d[0] = s[0]; d[1] = s[1]; d[2] = s[2]; d[3] = s[3];
    }
    __syncthreads();
#pragma unroll 8
    for (int kk = 0; kk < KC; ++kk) {
      const float4 wA = *(const float4*)(Ws + kk * WP + c0);
      const float4 wB = *(const float4*)(Ws + kk * WP + c0 + 4);
#pragma unroll
      for (int rr = 0; rr < 4; ++rr) {
        const float a = Hs[(r0 + rr) * HP + k0 + kk];
        acc[rr][0].x = fmaf(a, wA.x, acc[rr][0].x);
        acc[rr][0].y = fmaf(a, wA.y, acc[rr][0].y);
        acc[rr][0].z = fmaf(a, wA.z, acc[rr][0].z);
        acc[rr][0].w = fmaf(a, wA.w, acc[rr][0].w);
        acc[rr][1].x = fmaf(a, wB.x, acc[rr][1].x);
        acc[rr][1].y = fmaf(a, wB.y, acc[rr][1].y);
        acc[rr][1].z = fmaf(a, wB.z, acc[rr][1].z);
        acc[rr][1].w = fmaf(a, wB.w, acc[rr][1].w);
      }
    }
  }

  // bias2 + relu, store to d_out, BN partials
  const float4 b2A = *(const float4*)(b2 + c0);
  const float4 b2B = *(const float4*)(b2 + c0 + 4);
  float s[8], q2[8];
#pragma unroll
  for (int cc = 0; cc < 8; ++cc) { s[cc] = 0.f; q2[cc] = 0.f; }
#pragma unroll
  for (int rr = 0; rr < 4; ++rr) {
    const int n = n0 + r0 + rr;
    float4 hA, hB;
    hA.x = fmaxf(acc[rr][0].x + b2A.x, 0.f);
    hA.y = fmaxf(acc[rr][0].y + b2A.y, 0.f);
    hA.z = fmaxf(acc[rr][0].z + b2A.z, 0.f);
    hA.w = fmaxf(acc[rr][0].w + b2A.w, 0.f);
    hB.x = fmaxf(acc[rr][1].x + b2B.x, 0.f);
    hB.y = fmaxf(acc[rr][1].y + b2B.y, 0.f);
    hB.z = fmaxf(acc[rr][1].z + b2B.z, 0.f);
    hB.w = fmaxf(acc[rr][1].w + b2B.w, 0.f);
    if (n < N_NODES) {
      *(float4*)(out + (size_t)n * (NLAYERS * DIM) + lcol + c0) = hA;
      *(float4*)(out + (size_t)n * (NLAYERS * DIM) + lcol + c0 + 4) = hB;
      s[0] += hA.x; s[1] += hA.y; s[2] += hA.z; s[3] += hA.w;
      s[4] += hB.x; s[5] += hB.y; s[6] += hB.z; s[7] += hB.w;
      q2[0] += hA.x * hA.x; q2[1] += hA.y * hA.y;
      q2[2] += hA.z * hA.z; q2[3] += hA.w * hA.w;
      q2[4] += hB.x * hB.x; q2[5] += hB.y * hB.y;
      q2[6] += hB.z * hB.z; q2[7] += hB.w * hB.w;
    }
  }
  __syncthreads();  // Hs dead; reuse as red[16][128]
#pragma unroll
  for (int cc = 0; cc < 8; ++cc) red[rg * 128 + c0 + cc] = s[cc];
  __syncthreads();
  if (tid < 128) {
    float t = 0.f;
#pragma unroll
    for (int g = 0; g < 16; ++g) t += red[g * 128 + tid];
    unsafeAtomicAdd(&bnsum[tid], t);
  }
  __syncthreads();
#pragma unroll
  for (int cc = 0; cc < 8; ++cc) red[rg * 128 + c0 + cc] = q2[cc];
  __syncthreads();
  if (tid < 128) {
    float t = 0.f;
#pragma unroll
    for (int g = 0; g < 16; ++g) t += red[g * 128 + tid];
    unsafeAtomicAdd(&bnsum[128 + tid], t);
  }
}

// ---------------- BN finalize + normalize ----------------
__global__ __launch_bounds__(128) void bn_finalize_kernel(
    const float* __restrict__ bnsum, const float* __restrict__ gamma,
    const float* __restrict__ beta, float* __restrict__ bnfin) {
  const int c = threadIdx.x;
  const float inv_n = 1.f / (float)N_NODES;
  const float mu = bnsum[c] * inv_n;
  const float var = bnsum[128 + c] * inv_n - mu * mu;
  const float inv = rsqrtf(var + BN_EPS);
  const float sc = gamma[c] * inv;
  bnfin[c] = sc;
  bnfin[128 + c] = beta[c] - mu * sc;
}

__global__ __launch_bounds__(256) void bn_norm_kernel(float* __restrict__ zcol,
                                                      const float* __restrict__ bnfin) {
  const int idx = blockIdx.x * 256 + threadIdx.x;
  if (idx >= N_NODES * 32) return;
  const int n = idx >> 5, c4 = idx & 31;
  const float4 sc = ((const float4*)bnfin)[c4];
  const float4 sh = ((const float4*)(bnfin + 128))[c4];
  float4* p = (float4*)(zcol + (size_t)n * (NLAYERS * DIM)) + c4;
  float4 v = *p;
  v.x = fmaf(v.x, sc.x, sh.x);
  v.y = fmaf(v.y, sc.y, sh.y);
  v.z = fmaf(v.z, sc.z, sh.z);
  v.w = fmaf(v.w, sc.w, sh.w);
  *p = v;
}

// ---------------- graph pooling (batch is sorted) ----------------
__global__ __launch_bounds__(128) void pool_kernel(const float* __restrict__ zout,
                                                   const int* __restrict__ batch,
                                                   float* __restrict__ gout) {
  const int g = blockIdx.x / 3;
  const int chunk = blockIdx.x % 3;
  const int c = chunk * 128 + threadIdx.x;
  int lo = 0, hi = N_NODES;
  while (lo < hi) {
    const int m = (lo + hi) >> 1;
    if (batch[m] < g) lo = m + 1; else hi = m;
  }
  int lo2 = lo, hi2 = N_NODES;
  while (lo2 < hi2) {
    const int m = (lo2 + hi2) >> 1;
    if (batch[m] < g + 1) lo2 = m + 1; else hi2 = m;
  }
  float acc = 0.f;
  for (int n = lo; n < lo2; ++n) acc += zout[(size_t)n * (NLAYERS * DIM) + c];
  gout[(size_t)g * (NLAYERS * DIM) + c] = acc;
}

// ---------------- launch ----------------
extern "C" void kernel_launch(void* const* d_in, const int* in_sizes, int n_in,
                              void* d_out, int out_size, void* d_ws, size_t ws_size,
                              hipStream_t stream) {
  const float* x = (const float*)d_in[0];
  const int* ei = (const int*)d_in[1];
  const int* src = ei;
  const int* dst = ei + N_EDGES;
  const int* batch = (const int*)d_in[2];
  const float* W1 = (const float*)d_in[3];
  const float* b1 = (const float*)d_in[4];
  const float* W2 = (const float*)d_in[5];
  const float* b2 = (const float*)d_in[6];
  const float* gamma = (const float*)d_in[7];
  const float* beta = (const float*)d_in[8];
  float* out = (float*)d_out;
  float* gout = out + (size_t)N_NODES * NLAYERS * DIM;

  char* ws = (char*)d_ws;
  size_t off = 0;
  auto alloc = [&](size_t bytes) -> void* {
    off = (off + 511) & ~(size_t)511;
    void* p = ws + off;
    off += bytes;
    return p;
  };
  int* row_ptr = (int*)alloc((N_NODES + 1) * sizeof(int));
  int* cursor = (int*)alloc(N_NODES * sizeof(int));
  int* deg = (int*)alloc(N_NODES * sizeof(int));
  int* col = (int*)alloc(N_EDGES * sizeof(int));
  float* agg = (float*)alloc((size_t)N_NODES * DIM * sizeof(float));
  float* bnsum = (float*)alloc(NLAYERS * 256 * sizeof(float));
  float* bnfin = (float*)alloc(NLAYERS * 256 * sizeof(float));

  hipMemsetAsync(deg, 0, N_NODES * sizeof(int), stream);
  hipMemsetAsync(bnsum, 0, NLAYERS * 256 * sizeof(float), stream);

  hist_kernel<<<2048, 256, 0, stream>>>(dst, deg);
  scan_kernel<<<1, 1024, 0, stream>>>(deg, row_ptr, cursor);
  fill_kernel<<<2048, 256, 0, stream>>>(src, dst, cursor, col);

  for (int l = 0; l < NLAYERS; ++l) {
    const float* zin = (l == 0) ? x : (out + (size_t)(l - 1) * DIM);
    const int zstride = (l == 0) ? DIM : NLAYERS * DIM;
    agg_kernel<<<(N_NODES * 64 + 255) / 256, 256, 0, stream>>>(zin, zstride,
                                                               row_ptr, col, agg);
    mlp_kernel<<<(N_NODES + RT - 1) / RT, 256, 0, stream>>>(
        agg, W1 + (size_t)l * DIM * DIM, b1 + (size_t)l * DIM,
        W2 + (size_t)l * DIM * DIM, b2 + (size_t)l * DIM, out, l * DIM,
        bnsum + l * 256);
    bn_finalize_kernel<<<1, 128, 0, stream>>>(bnsum + l * 256, gamma + l * DIM,
                                              beta + l * DIM, bnfin + l * 256);
    bn_norm_kernel<<<(N_NODES * 32 + 255) / 256, 256, 0, stream>>>(
        out + (size_t)l * DIM, bnfin + l * 256);
  }
  pool_kernel<<<NGRAPHS * 3, 128, 0, stream>>>(out, batch, gout);
}

// Round 4
// 1159.430 us; speedup vs baseline: 1.2147x; 1.2147x over previous
//
#include <hip/hip_runtime.h>

#define N_NODES 100000
#define N_EDGES 1600000
#define DIM 128
#define NLAYERS 3
#define NGRAPHS 512
#define BN_EPS 1e-5f

#define RT 64      // rows per MLP block
#define KC 32      // k-chunk
#define XP 36      // Xs padded stride (words) -> 2-way-free LDS banks
#define WP 132     // Ws padded stride
#define HP 132     // Hs padded stride

#define SCHUNK 512                                  // nodes per scan block
#define SBLOCKS ((N_NODES + SCHUNK - 1) / SCHUNK)   // 196

// ---------------- CSR build ----------------
__global__ __launch_bounds__(256) void hist_kernel(const int* __restrict__ dst,
                                                   int* __restrict__ deg) {
  for (int e = blockIdx.x * blockDim.x + threadIdx.x; e < N_EDGES;
       e += gridDim.x * blockDim.x)
    atomicAdd(&deg[dst[e]], 1);
}

// stage 1: per-block sums of deg (coalesced int2 loads)
__global__ __launch_bounds__(256) void partial_kernel(const int* __restrict__ deg,
                                                      int* __restrict__ bsum) {
  __shared__ int red[256];
  const int t = threadIdx.x;
  const int i0 = blockIdx.x * SCHUNK + 2 * t;
  int s = 0;
  if (i0 + 1 < N_NODES) {
    const int2 v = *(const int2*)(deg + i0);
    s = v.x + v.y;
  } else if (i0 < N_NODES) {
    s = deg[i0];
  }
  red[t] = s;
  __syncthreads();
  for (int off = 128; off > 0; off >>= 1) {
    if (t < off) red[t] += red[t + off];
    __syncthreads();
  }
  if (t == 0) bsum[blockIdx.x] = red[0];
}

// stage 2: scan the 196 block sums (single tiny block), write row_ptr[N]
__global__ __launch_bounds__(256) void bscan_kernel(const int* __restrict__ bsum,
                                                    int* __restrict__ boff,
                                                    int* __restrict__ row_ptr) {
  __shared__ int s[256];
  const int t = threadIdx.x;
  const int v = (t < SBLOCKS) ? bsum[t] : 0;
  s[t] = v;
  __syncthreads();
  for (int off = 1; off < 256; off <<= 1) {
    int u = (t >= off) ? s[t - off] : 0;
    __syncthreads();
    s[t] += u;
    __syncthreads();
  }
  if (t < SBLOCKS) boff[t] = s[t] - v;  // exclusive
  if (t == SBLOCKS - 1) row_ptr[N_NODES] = s[t];
}

// stage 3: per-block exclusive scan over pairs, emit row_ptr + cursor
__global__ __launch_bounds__(256) void emit_kernel(const int* __restrict__ deg,
                                                   const int* __restrict__ boff,
                                                   int* __restrict__ row_ptr,
                                                   int* __restrict__ cursor) {
  __shared__ int s[256];
  const int t = threadIdx.x;
  const int i0 = blockIdx.x * SCHUNK + 2 * t;
  int d0 = 0, d1 = 0;
  if (i0 + 1 < N_NODES) {
    const int2 v = *(const int2*)(deg + i0);
    d0 = v.x; d1 = v.y;
  } else if (i0 < N_NODES) {
    d0 = deg[i0];
  }
  const int pair = d0 + d1;
  s[t] = pair;
  __syncthreads();
  for (int off = 1; off < 256; off <<= 1) {
    int u = (t >= off) ? s[t - off] : 0;
    __syncthreads();
    s[t] += u;
    __syncthreads();
  }
  const int base = boff[blockIdx.x] + s[t] - pair;  // exclusive within block
  if (i0 + 1 < N_NODES) {
    const int2 rp = make_int2(base, base + d0);
    *(int2*)(row_ptr + i0) = rp;
    *(int2*)(cursor + i0) = rp;
  } else if (i0 < N_NODES) {
    row_ptr[i0] = base;
    cursor[i0] = base;
  }
}

__global__ __launch_bounds__(256) void fill_kernel(const int* __restrict__ src,
                                                   const int* __restrict__ dst,
                                                   int* __restrict__ cursor,
                                                   int* __restrict__ col) {
  for (int e = blockIdx.x * blockDim.x + threadIdx.x; e < N_EDGES;
       e += gridDim.x * blockDim.x) {
    const int d = dst[e];
    const int pos = atomicAdd(&cursor[d], 1);
    col[pos] = src[e];
  }
}

// ---------------- aggregation: agg[i] = z[i] + sum_{j in N(i)} z[j] ----------------
__global__ __launch_bounds__(256) void agg_kernel(const float* __restrict__ zin,
                                                  int zstride,
                                                  const int* __restrict__ row_ptr,
                                                  const int* __restrict__ col,
                                                  float* __restrict__ agg) {
  const int w = (blockIdx.x * 256 + threadIdx.x) >> 6;  // one wave per node
  const int lane = threadIdx.x & 63;
  if (w >= N_NODES) return;
  const int start = row_ptr[w];
  const int end = row_ptr[w + 1];

  float2 acc = ((const float2*)(zin + (size_t)w * zstride))[lane];  // + z[i]
  int j = start;
  // 8 independent row-loads in flight for latency hiding (avg degree 16)
  for (; j + 8 <= end; j += 8) {
    const int c0 = col[j], c1 = col[j + 1], c2 = col[j + 2], c3 = col[j + 3];
    const int c4 = col[j + 4], c5 = col[j + 5], c6 = col[j + 6], c7 = col[j + 7];
    const float2 v0 = ((const float2*)(zin + (size_t)c0 * zstride))[lane];
    const float2 v1 = ((const float2*)(zin + (size_t)c1 * zstride))[lane];
    const float2 v2 = ((const float2*)(zin + (size_t)c2 * zstride))[lane];
    const float2 v3 = ((const float2*)(zin + (size_t)c3 * zstride))[lane];
    const float2 v4 = ((const float2*)(zin + (size_t)c4 * zstride))[lane];
    const float2 v5 = ((const float2*)(zin + (size_t)c5 * zstride))[lane];
    const float2 v6 = ((const float2*)(zin + (size_t)c6 * zstride))[lane];
    const float2 v7 = ((const float2*)(zin + (size_t)c7 * zstride))[lane];
    acc.x += ((v0.x + v1.x) + (v2.x + v3.x)) + ((v4.x + v5.x) + (v6.x + v7.x));
    acc.y += ((v0.y + v1.y) + (v2.y + v3.y)) + ((v4.y + v5.y) + (v6.y + v7.y));
  }
  for (; j + 4 <= end; j += 4) {
    const int c0 = col[j], c1 = col[j + 1], c2 = col[j + 2], c3 = col[j + 3];
    const float2 v0 = ((const float2*)(zin + (size_t)c0 * zstride))[lane];
    const float2 v1 = ((const float2*)(zin + (size_t)c1 * zstride))[lane];
    const float2 v2 = ((const float2*)(zin + (size_t)c2 * zstride))[lane];
    const float2 v3 = ((const float2*)(zin + (size_t)c3 * zstride))[lane];
    acc.x += (v0.x + v1.x) + (v2.x + v3.x);
    acc.y += (v0.y + v1.y) + (v2.y + v3.y);
  }
  for (; j < end; ++j) {
    const int c = col[j];
    const float2 v = ((const float2*)(zin + (size_t)c * zstride))[lane];
    acc.x += v.x;
    acc.y += v.y;
  }
  ((float2*)(agg + (size_t)w * DIM))[lane] = acc;
}

// ---------------- fused MLP: h2 = relu(relu(X@W1+b1)@W2+b2) + BN partials ----------------
__global__ __launch_bounds__(256) void mlp_kernel(
    const float* __restrict__ X,                       // agg [N,128]
    const float* __restrict__ W1, const float* __restrict__ b1,
    const float* __restrict__ W2, const float* __restrict__ b2,
    float* __restrict__ out,                           // d_out, row stride 384
    int lcol,                                          // l*128
    float* __restrict__ bnsum) {                       // [256]: sum | sumsq
  __shared__ float smem[32 * WP + RT * HP];  // 12672 floats = 50688 B
  float* Ws = smem;            // 32 x WP
  float* Xs = smem + 32 * WP;  // phase1: 64 x XP (2304 floats, fits region)
  float* Hs = smem + 32 * WP;  // phase2: 64 x HP
  float* red = smem + 32 * WP; // epilogue: 16 x 128

  const int tid = threadIdx.x;
  const int cg = tid & 15, rg = tid >> 4;
  const int c0 = cg * 8, r0 = rg * 4;
  const int n0 = blockIdx.x * RT;

  float4 acc[4][2];
#pragma unroll
  for (int rr = 0; rr < 4; ++rr) {
    acc[rr][0] = make_float4(0.f, 0.f, 0.f, 0.f);
    acc[rr][1] = make_float4(0.f, 0.f, 0.f, 0.f);
  }

  // ---- phase 1: h1 = relu(X@W1 + b1) ----
  for (int kc = 0; kc < DIM / KC; ++kc) {
    const int k0 = kc * KC;
    __syncthreads();
    {  // stage W1 rows k0..k0+31 (fully coalesced 16KB)
      const int kk = tid >> 3, q = tid & 7;
      const float4* s = (const float4*)(W1 + (size_t)(k0 + kk) * DIM + q * 16);
      float4* d = (float4*)(Ws + kk * WP + q * 16);
      d[0] = s[0]; d[1] = s[1]; d[2] = s[2]; d[3] = s[3];
    }
    {  // stage X cols k0..k0+31 for 64 rows
      const int i = tid >> 2, q = tid & 3;
      const int n = n0 + i;
      float4 v0 = make_float4(0, 0, 0, 0), v1 = v0;
      if (n < N_NODES) {
        const float4* s = (const float4*)(X + (size_t)n * DIM + k0 + q * 8);
        v0 = s[0]; v1 = s[1];
      }
      float4* d = (float4*)(Xs + i * XP + q * 8);
      d[0] = v0; d[1] = v1;
    }
    __syncthreads();
#pragma unroll 8
    for (int kk = 0; kk < KC; ++kk) {
      const float4 wA = *(const float4*)(Ws + kk * WP + c0);
      const float4 wB = *(const float4*)(Ws + kk * WP + c0 + 4);
#pragma unroll
      for (int rr = 0; rr < 4; ++rr) {
        const float a = Xs[(r0 + rr) * XP + kk];
        acc[rr][0].x = fmaf(a, wA.x, acc[rr][0].x);
        acc[rr][0].y = fmaf(a, wA.y, acc[rr][0].y);
        acc[rr][0].z = fmaf(a, wA.z, acc[rr][0].z);
        acc[rr][0].w = fmaf(a, wA.w, acc[rr][0].w);
        acc[rr][1].x = fmaf(a, wB.x, acc[rr][1].x);
        acc[rr][1].y = fmaf(a, wB.y, acc[rr][1].y);
        acc[rr][1].z = fmaf(a, wB.z, acc[rr][1].z);
        acc[rr][1].w = fmaf(a, wB.w, acc[rr][1].w);
      }
    }
  }

  // bias1 + relu -> Hs
  const float4 b1A = *(const float4*)(b1 + c0);
  const float4 b1B = *(const float4*)(b1 + c0 + 4);
  __syncthreads();
#pragma unroll
  for (int rr = 0; rr < 4; ++rr) {
    float4 hA, hB;
    hA.x = fmaxf(acc[rr][0].x + b1A.x, 0.f);
    hA.y = fmaxf(acc[rr][0].y + b1A.y, 0.f);
    hA.z = fmaxf(acc[rr][0].z + b1A.z, 0.f);
    hA.w = fmaxf(acc[rr][0].w + b1A.w, 0.f);
    hB.x = fmaxf(acc[rr][1].x + b1B.x, 0.f);
    hB.y = fmaxf(acc[rr][1].y + b1B.y, 0.f);
    hB.z = fmaxf(acc[rr][1].z + b1B.z, 0.f);
    hB.w = fmaxf(acc[rr][1].w + b1B.w, 0.f);
    *(float4*)(Hs + (r0 + rr) * HP + c0) = hA;
    *(float4*)(Hs + (r0 + rr) * HP + c0 + 4) = hB;
    acc[rr][0] = make_float4(0.f, 0.f, 0.f, 0.f);
    acc[rr][1] = make_float4(0.f, 0.f, 0.f, 0.f);
  }

  // ---- phase 2: h2 = relu(h1@W2 + b2) ----
  for (int kc = 0; kc < DIM / KC; ++kc) {
    const int k0 = kc * KC;
    __syncthreads();
    {  // stage W2 rows k0..k0+31
      const int kk = tid >> 3, q = tid & 7;
      const float4* s = (const float4*)(W2 + (size_t)(k0 + kk) * DIM + q * 16);
      float4* d = (float4*)(Ws + kk * WP + q * 16);
      d[0] = s[0]; d[1] = s[1]; d[2] = s[2]; d[3] = s[3];
    }
    __syncthreads();
#pragma unroll 8
    for (int kk = 0; kk < KC; ++kk) {
      const float4 wA = *(const float4*)(Ws + kk * WP + c0);
      const float4 wB = *(const float4*)(Ws + kk * WP + c0 + 4);
#pragma unroll
      for (int rr = 0; rr < 4; ++rr) {
        const float a = Hs[(r0 + rr) * HP + k0 + kk];
        acc[rr][0].x = fmaf(a, wA.x, acc[rr][0].x);
        acc[rr][0].y = fmaf(a, wA.y, acc[rr][0].y);
        acc[rr][0].z = fmaf(a, wA.z, acc[rr][0].z);
        acc[rr][0].w = fmaf(a, wA.w, acc[rr][0].w);
        acc[rr][1].x = fmaf(a, wB.x, acc[rr][1].x);
        acc[rr][1].y = fmaf(a, wB.y, acc[rr][1].y);
        acc[rr][1].z = fmaf(a, wB.z, acc[rr][1].z);
        acc[rr][1].w = fmaf(a, wB.w, acc[rr][1].w);
      }
    }
  }

  // bias2 + relu, store to d_out, BN partials
  const float4 b2A = *(const float4*)(b2 + c0);
  const float4 b2B = *(const float4*)(b2 + c0 + 4);
  float s[8], q2[8];
#pragma unroll
  for (int cc = 0; cc < 8; ++cc) { s[cc] = 0.f; q2[cc] = 0.f; }
#pragma unroll
  for (int rr = 0; rr < 4; ++rr) {
    const int n = n0 + r0 + rr;
    float4 hA, hB;
    hA.x = fmaxf(acc[rr][0].x + b2A.x, 0.f);
    hA.y = fmaxf(acc[rr][0].y + b2A.y, 0.f);
    hA.z = fmaxf(acc[rr][0].z + b2A.z, 0.f);
    hA.w = fmaxf(acc[rr][0].w + b2A.w, 0.f);
    hB.x = fmaxf(acc[rr][1].x + b2B.x, 0.f);
    hB.y = fmaxf(acc[rr][1].y + b2B.y, 0.f);
    hB.z = fmaxf(acc[rr][1].z + b2B.z, 0.f);
    hB.w = fmaxf(acc[rr][1].w + b2B.w, 0.f);
    if (n < N_NODES) {
      *(float4*)(out + (size_t)n * (NLAYERS * DIM) + lcol + c0) = hA;
      *(float4*)(out + (size_t)n * (NLAYERS * DIM) + lcol + c0 + 4) = hB;
      s[0] += hA.x; s[1] += hA.y; s[2] += hA.z; s[3] += hA.w;
      s[4] += hB.x; s[5] += hB.y; s[6] += hB.z; s[7] += hB.w;
      q2[0] += hA.x * hA.x; q2[1] += hA.y * hA.y;
      q2[2] += hA.z * hA.z; q2[3] += hA.w * hA.w;
      q2[4] += hB.x * hB.x; q2[5] += hB.y * hB.y;
      q2[6] += hB.z * hB.z; q2[7] += hB.w * hB.w;
    }
  }
  __syncthreads();  // Hs dead; reuse as red[16][128]
#pragma unroll
  for (int cc = 0; cc < 8; ++cc) red[rg * 128 + c0 + cc] = s[cc];
  __syncthreads();
  if (tid < 128) {
    float t = 0.f;
#pragma unroll
    for (int g = 0; g < 16; ++g) t += red[g * 128 + tid];
    unsafeAtomicAdd(&bnsum[tid], t);
  }
  __syncthreads();
#pragma unroll
  for (int cc = 0; cc < 8; ++cc) red[rg * 128 + c0 + cc] = q2[cc];
  __syncthreads();
  if (tid < 128) {
    float t = 0.f;
#pragma unroll
    for (int g = 0; g < 16; ++g) t += red[g * 128 + tid];
    unsafeAtomicAdd(&bnsum[128 + tid], t);
  }
}

// ---------------- BN finalize + normalize ----------------
__global__ __launch_bounds__(128) void bn_finalize_kernel(
    const float* __restrict__ bnsum, const float* __restrict__ gamma,
    const float* __restrict__ beta, float* __restrict__ bnfin) {
  const int c = threadIdx.x;
  const float inv_n = 1.f / (float)N_NODES;
  const float mu = bnsum[c] * inv_n;
  const float var = bnsum[128 + c] * inv_n - mu * mu;
  const float inv = rsqrtf(var + BN_EPS);
  const float sc = gamma[c] * inv;
  bnfin[c] = sc;
  bnfin[128 + c] = beta[c] - mu * sc;
}

__global__ __launch_bounds__(256) void bn_norm_kernel(float* __restrict__ zcol,
                                                      const float* __restrict__ bnfin) {
  const int idx = blockIdx.x * 256 + threadIdx.x;
  if (idx >= N_NODES * 32) return;
  const int n = idx >> 5, c4 = idx & 31;
  const float4 sc = ((const float4*)bnfin)[c4];
  const float4 sh = ((const float4*)(bnfin + 128))[c4];
  float4* p = (float4*)(zcol + (size_t)n * (NLAYERS * DIM)) + c4;
  float4 v = *p;
  v.x = fmaf(v.x, sc.x, sh.x);
  v.y = fmaf(v.y, sc.y, sh.y);
  v.z = fmaf(v.z, sc.z, sh.z);
  v.w = fmaf(v.w, sc.w, sh.w);
  *p = v;
}

// ---------------- graph pooling (batch is sorted) ----------------
__global__ __launch_bounds__(128) void pool_kernel(const float* __restrict__ zout,
                                                   const int* __restrict__ batch,
                                                   float* __restrict__ gout) {
  const int g = blockIdx.x / 3;
  const int chunk = blockIdx.x % 3;
  const int c = chunk * 128 + threadIdx.x;
  int lo = 0, hi = N_NODES;
  while (lo < hi) {
    const int m = (lo + hi) >> 1;
    if (batch[m] < g) lo = m + 1; else hi = m;
  }
  int lo2 = lo, hi2 = N_NODES;
  while (lo2 < hi2) {
    const int m = (lo2 + hi2) >> 1;
    if (batch[m] < g + 1) lo2 = m + 1; else hi2 = m;
  }
  float acc = 0.f;
  for (int n = lo; n < lo2; ++n) acc += zout[(size_t)n * (NLAYERS * DIM) + c];
  gout[(size_t)g * (NLAYERS * DIM) + c] = acc;
}

// ---------------- launch ----------------
extern "C" void kernel_launch(void* const* d_in, const int* in_sizes, int n_in,
                              void* d_out, int out_size, void* d_ws, size_t ws_size,
                              hipStream_t stream) {
  const float* x = (const float*)d_in[0];
  const int* ei = (const int*)d_in[1];
  const int* src = ei;
  const int* dst = ei + N_EDGES;
  const int* batch = (const int*)d_in[2];
  const float* W1 = (const float*)d_in[3];
  const float* b1 = (const float*)d_in[4];
  const float* W2 = (const float*)d_in[5];
  const float* b2 = (const float*)d_in[6];
  const float* gamma = (const float*)d_in[7];
  const float* beta = (const float*)d_in[8];
  float* out = (float*)d_out;
  float* gout = out + (size_t)N_NODES * NLAYERS * DIM;

  char* ws = (char*)d_ws;
  size_t off = 0;
  auto alloc = [&](size_t bytes) -> void* {
    off = (off + 511) & ~(size_t)511;
    void* p = ws + off;
    off += bytes;
    return p;
  };
  int* row_ptr = (int*)alloc((N_NODES + 1) * sizeof(int));
  int* cursor = (int*)alloc(N_NODES * sizeof(int));
  int* deg = (int*)alloc(N_NODES * sizeof(int));
  int* col = (int*)alloc(N_EDGES * sizeof(int));
  int* bsum = (int*)alloc(SBLOCKS * sizeof(int));
  int* boff = (int*)alloc(SBLOCKS * sizeof(int));
  float* agg = (float*)alloc((size_t)N_NODES * DIM * sizeof(float));
  float* bnsum = (float*)alloc(NLAYERS * 256 * sizeof(float));
  float* bnfin = (float*)alloc(NLAYERS * 256 * sizeof(float));

  hipMemsetAsync(deg, 0, N_NODES * sizeof(int), stream);
  hipMemsetAsync(bnsum, 0, NLAYERS * 256 * sizeof(float), stream);

  hist_kernel<<<2048, 256, 0, stream>>>(dst, deg);
  partial_kernel<<<SBLOCKS, 256, 0, stream>>>(deg, bsum);
  bscan_kernel<<<1, 256, 0, stream>>>(bsum, boff, row_ptr);
  emit_kernel<<<SBLOCKS, 256, 0, stream>>>(deg, boff, row_ptr, cursor);
  fill_kernel<<<2048, 256, 0, stream>>>(src, dst, cursor, col);

  for (int l = 0; l < NLAYERS; ++l) {
    const float* zin = (l == 0) ? x : (out + (size_t)(l - 1) * DIM);
    const int zstride = (l == 0) ? DIM : NLAYERS * DIM;
    agg_kernel<<<(N_NODES * 64 + 255) / 256, 256, 0, stream>>>(zin, zstride,
                                                               row_ptr, col, agg);
    mlp_kernel<<<(N_NODES + RT - 1) / RT, 256, 0, stream>>>(
        agg, W1 + (size_t)l * DIM * DIM, b1 + (size_t)l * DIM,
        W2 + (size_t)l * DIM * DIM, b2 + (size_t)l * DIM, out, l * DIM,
        bnsum + l * 256);
    bn_finalize_kernel<<<1, 128, 0, stream>>>(bnsum + l * 256, gamma + l * DIM,
                                              beta + l * DIM, bnfin + l * 256);
    bn_norm_kernel<<<(N_NODES * 32 + 255) / 256, 256, 0, stream>>>(
        out + (size_t)l * DIM, bnfin + l * 256);
  }
  pool_kernel<<<NGRAPHS * 3, 128, 0, stream>>>(out, batch, gout);
}